// Round 2
// baseline (13825.215 us; speedup 1.0000x reference)
//
#include <hip/hip_runtime.h>
#include <math.h>

// Problem constants (4, 19, 512, 512) fp32
#define BB 4
#define CC 19
#define HH 512
#define WW 512
#define NSLICE (BB * CC)        // 76
#define SLICE  (HH * WW)        // 262144
#define W4     (WW / 4)         // 128 float4 per row
#define EPS    1e-12f
#define NEGINF (-INFINITY)

// time-tiling params
#define TSTEPS 16
#define RROWS  64
#define AROWS  (RROWS + 2 * TSTEPS)   // 96 rows held in registers per thread
#define NPASS  (256 / TSTEPS)         // 16 passes
#define RBLK   (HH / RROWS)           // 8 row-blocks per slice

// ---------------------------------------------------------------------------
// init: cur0 = -x, border (i==0, i==511, j==0, j==511) = 1.0
__global__ void init_kernel(const float* __restrict__ x, float* __restrict__ cur) {
    int t = blockIdx.x * blockDim.x + threadIdx.x;   // over NSLICE*SLICE/4
    const float4* x4 = (const float4*)x;
    float4* c4 = (float4*)cur;
    float4 v = x4[t];
    int pix = t << 2;
    int s = pix & (SLICE - 1);
    int i = s >> 9;
    int j0 = s & 511;
    float4 o;
    o.x = -v.x; o.y = -v.y; o.z = -v.z; o.w = -v.w;
    if (i == 0 || i == HH - 1) {
        o.x = 1.0f; o.y = 1.0f; o.z = 1.0f; o.w = 1.0f;
    } else {
        if (j0 == 0)        o.x = 1.0f;
        if (j0 == WW - 4)   o.w = 1.0f;
    }
    c4[t] = o;
}

// ---------------------------------------------------------------------------
// one pass = TSTEPS fused maxpool*x steps.
// Block: 512 threads (8 waves) spanning the full 512-col width; thread = 1 column.
// Each thread holds AROWS rows of cur and x in registers. Horizontal 3-max via
// wave shuffles; cross-wave boundary columns via a double-buffered LDS snapshot.
// Vertical 3-max via rolling carry over the thread's own register column.
__global__ __launch_bounds__(512, 2)
void pass_kernel(const float* __restrict__ in, const float* __restrict__ xg,
                 float* __restrict__ out) {
    const int tid  = threadIdx.x;        // column 0..511
    const int lane = tid & 63;
    const int wv   = tid >> 6;           // wave 0..7
    const int bc   = blockIdx.x / RBLK;  // slice 0..75
    const int brow = blockIdx.x % RBLK;  // row-block 0..7
    const int gstart = brow * RROWS - TSTEPS;

    // L63[p][w][a] = left-neighbor value for wave w (written by lane63 of wave w-1)
    // R0 [p][w][a] = value written by lane0 of wave w; read by lane63 of wave w-1 (as slot w)
    //   reader: lane0 of wave w  reads L63[p][w][a]
    //           lane63 of wave w reads R0[p][w+1][a]
    //   writer: lane63 of wave w writes L63[p][w+1][a]
    //           lane0  of wave w writes R0[p][w][a]
    //   prefilled -inf: L63[p][0][*], R0[p][8][*]
    __shared__ float L63[2][9][AROWS];
    __shared__ float R0[2][9][AROWS];

    if (tid < AROWS) {
        L63[0][0][tid] = NEGINF; L63[1][0][tid] = NEGINF;
        R0[0][8][tid]  = NEGINF; R0[1][8][tid]  = NEGINF;
    }

    // load register tiles (coalesced: thread j reads column j)
    float cur[AROWS], xr[AROWS];
    const size_t sbase = (size_t)bc * SLICE;
#pragma unroll
    for (int a = 0; a < AROWS; ++a) {
        int grow = gstart + a;
        if (grow >= 0 && grow < HH) {          // uniform branch
            cur[a] = in[sbase + (size_t)grow * WW + tid];
            xr[a]  = xg[sbase + (size_t)grow * WW + tid];
        } else {
            cur[a] = NEGINF;
            xr[a]  = 1.0f;
        }
    }

    const float* rbase[2];
    rbase[0] = (lane == 63) ? &R0[0][wv + 1][0] : &L63[0][wv][0];
    rbase[1] = (lane == 63) ? &R0[1][wv + 1][0] : &L63[1][wv][0];
    float* wbase[2];
    wbase[0] = (lane == 63) ? &L63[0][wv + 1][0] : &R0[0][wv][0];
    wbase[1] = (lane == 63) ? &L63[1][wv + 1][0] : &R0[1][wv][0];

#pragma unroll
    for (int t = 1; t <= TSTEPS; ++t) {
        const int p = t & 1;
        // snapshot boundary columns (pre-step values) for rows read this step
        if (lane == 0 || lane == 63) {
            float* wp = wbase[p];
#pragma unroll
            for (int a = t - 1; a <= AROWS - t; ++a) wp[a] = cur[a];
        }
        __syncthreads();
        const float* rp = rbase[p];

        // hmax of a row: shuffle left/right within wave, LDS for wave-boundary lanes
        auto hmax = [&](float v, int a) -> float {
            float l = __shfl_up(v, 1);
            float r = __shfl_down(v, 1);
            float b = rp[a];
            l = (lane == 0)  ? b : l;
            r = (lane == 63) ? b : r;
            return fmaxf(fmaxf(l, v), r);
        };

        float hm1 = hmax(cur[t - 1], t - 1);
        float h0  = hmax(cur[t],     t);
#pragma unroll
        for (int r = t; r <= AROWS - 1 - t; ++r) {
            float hp1 = hmax(cur[r + 1], r + 1);
            cur[r] = fmaxf(fmaxf(hm1, h0), hp1) * xr[r];
            hm1 = h0; h0 = hp1;
        }
        // rows outside the image must stay -inf (maxpool pad semantics)
#pragma unroll
        for (int a = 0; a < AROWS; ++a) {
            if (a < TSTEPS || a >= AROWS - TSTEPS) {   // only candidates
                int grow = gstart + a;
                if (grow < 0 || grow >= HH) cur[a] = NEGINF;   // uniform
            }
        }
    }

    // store the R valid center rows
#pragma unroll
    for (int a = TSTEPS; a < TSTEPS + RROWS; ++a)
        out[sbase + (size_t)(gstart + a) * WW + tid] = cur[a];
}

// ---------------------------------------------------------------------------
// final: norm over channel dim (19), out = cur * x / max(||cur||_2, eps)
__global__ void norm_kernel(const float* __restrict__ cur,
                            const float* __restrict__ x,
                            float* __restrict__ out) {
    int t = blockIdx.x * blockDim.x + threadIdx.x;   // over BB * HH * W4
    int j4 = t & (W4 - 1);
    int i  = (t >> 7) & (HH - 1);
    int b  = t >> 16;
    size_t off = (size_t)b * CC * SLICE + (size_t)i * WW + (j4 << 2);

    float4 vals[CC];
    float sx = 0.f, sy = 0.f, sz = 0.f, sw = 0.f;
#pragma unroll
    for (int c = 0; c < CC; ++c) {
        float4 v = *(const float4*)(cur + off + (size_t)c * SLICE);
        vals[c] = v;
        sx += v.x * v.x; sy += v.y * v.y; sz += v.z * v.z; sw += v.w * v.w;
    }
    float4 r;
    r.x = 1.0f / fmaxf(sqrtf(sx), EPS);
    r.y = 1.0f / fmaxf(sqrtf(sy), EPS);
    r.z = 1.0f / fmaxf(sqrtf(sz), EPS);
    r.w = 1.0f / fmaxf(sqrtf(sw), EPS);
#pragma unroll
    for (int c = 0; c < CC; ++c) {
        float4 xv = *(const float4*)(x + off + (size_t)c * SLICE);
        float4 o;
        o.x = vals[c].x * xv.x * r.x;
        o.y = vals[c].y * xv.y * r.y;
        o.z = vals[c].z * xv.z * r.z;
        o.w = vals[c].w * xv.w * r.w;
        *(float4*)(out + off + (size_t)c * SLICE) = o;
    }
}

// ---------------------------------------------------------------------------
extern "C" void kernel_launch(void* const* d_in, const int* in_sizes, int n_in,
                              void* d_out, int out_size, void* d_ws, size_t ws_size,
                              hipStream_t stream) {
    const float* x = (const float*)d_in[0];
    float* out = (float*)d_out;
    float* ws  = (float*)d_ws;        // >= 79,691,776 B

    const int initBlocks = NSLICE * SLICE / 4 / 256; // 19456
    const int passBlocks = NSLICE * RBLK;            // 608
    const int normBlocks = BB * HH * W4 / 256;       // 1024

    init_kernel<<<initBlocks, 256, 0, stream>>>(x, ws);
    float* a = ws;
    float* b = out;
    for (int it = 0; it < NPASS; ++it) {
        pass_kernel<<<passBlocks, 512, 0, stream>>>(a, x, b);
        float* tmp = a; a = b; b = tmp;
    }
    // NPASS even -> result back in ws
    norm_kernel<<<normBlocks, 256, 0, stream>>>(ws, x, out);
}